// Round 1
// baseline (492.122 us; speedup 1.0000x reference)
//
#include <hip/hip_runtime.h>

#define B_   2
#define N_   32768
#define M_   4096
#define C_   128
#define OUT_ 128
#define IN_  131

// ---------------------------------------------------------------------------
// K1: brute-force 3-NN. One thread per query; sampled points (+|s|^2) in LDS.
// d2 computed with the reference's exact fp32 expansion (no fma contraction)
// so near-tie neighbor ordering matches the fp32 reference. Strict '<' keeps
// the lower index on ties, matching lax.top_k stability.
// ---------------------------------------------------------------------------
__global__ __launch_bounds__(256) void nn_kernel(const float* __restrict__ x,
                                                 const float* __restrict__ sx,
                                                 int4* __restrict__ idx_out) {
    __shared__ float4 spts[M_];   // 64 KB: s0,s1,s2,|s|^2
    const int qi = blockIdx.x * 256 + threadIdx.x;   // [0, 65536)
    const int b  = qi >> 15;                          // N_=32768
    const float* sxb = sx + (size_t)b * M_ * 3;
    for (int m = threadIdx.x; m < M_; m += 256) {
        float s0 = sxb[3*m+0], s1 = sxb[3*m+1], s2 = sxb[3*m+2];
        float ss = __fadd_rn(__fadd_rn(__fmul_rn(s0,s0), __fmul_rn(s1,s1)),
                             __fmul_rn(s2,s2));
        spts[m] = make_float4(s0, s1, s2, ss);
    }
    __syncthreads();

    const float x0 = x[(size_t)qi*3+0];
    const float x1 = x[(size_t)qi*3+1];
    const float x2 = x[(size_t)qi*3+2];
    const float xx = __fadd_rn(__fadd_rn(__fmul_rn(x0,x0), __fmul_rn(x1,x1)),
                               __fmul_rn(x2,x2));

    float b0 = 1e30f, b1v = 1e30f, b2v = 1e30f;
    int   i0 = 0,     i1 = 0,      i2 = 0;
    #pragma unroll 4
    for (int m = 0; m < M_; ++m) {
        float4 s = spts[m];
        float dot = __fadd_rn(__fadd_rn(__fmul_rn(x0,s.x), __fmul_rn(x1,s.y)),
                              __fmul_rn(x2,s.z));
        float d2 = __fadd_rn(__fsub_rn(xx, __fmul_rn(2.0f, dot)), s.w);
        if (d2 < b2v) {
            if (d2 < b1v) {
                b2v = b1v; i2 = i1;
                if (d2 < b0) { b1v = b0; i1 = i0; b0 = d2; i0 = m; }
                else         { b1v = d2; i1 = m; }
            } else { b2v = d2; i2 = m; }
        }
    }
    idx_out[qi] = make_int4(i0, i1, i2, 0);
}

// ---------------------------------------------------------------------------
// K2: gather 3 neighbor feature rows, average -> I[65536][128].
// 32 lanes (float4 each) per query; gathers are L2-resident (features = 4 MB).
// ---------------------------------------------------------------------------
__global__ __launch_bounds__(256) void interp_kernel(const float* __restrict__ features,
                                                     const int4* __restrict__ idx,
                                                     float4* __restrict__ I) {
    const int t    = blockIdx.x * 256 + threadIdx.x;
    const int qi   = t >> 5;
    const int lane = t & 31;
    const int b    = qi >> 15;
    const int4 v   = idx[qi];
    const float4* fb = (const float4*)features + (size_t)b * M_ * (C_/4);
    float4 f0 = fb[(size_t)v.x * 32 + lane];
    float4 f1 = fb[(size_t)v.y * 32 + lane];
    float4 f2 = fb[(size_t)v.z * 32 + lane];
    float4 r;
    r.x = ((f0.x + f1.x) + f2.x) / 3.0f;
    r.y = ((f0.y + f1.y) + f2.y) / 3.0f;
    r.z = ((f0.z + f1.z) + f2.z) / 3.0f;
    r.w = ((f0.w + f1.w) + f2.w) / 3.0f;
    I[(size_t)qi * 32 + lane] = r;
}

// ---------------------------------------------------------------------------
// K3: A = relu(I @ W1f^T + x @ W1x^T + b1).  128x128 C-tile per block,
// 256 threads, 8x8 micro-tile, K=128 in 8 chunks of 16 staged in LDS.
// The 3 xyz columns of w1 are folded into the epilogue.
// ---------------------------------------------------------------------------
__global__ __launch_bounds__(256) void gemm1_kernel(const float* __restrict__ I,
                                                    const float* __restrict__ x,
                                                    const float* __restrict__ w1,
                                                    const float* __restrict__ b1,
                                                    float* __restrict__ A) {
    __shared__ float sI[16][132];   // [k][row], padded
    __shared__ float sW[16][132];   // [k][out]
    const int row0 = blockIdx.x * 128;
    const int tid  = threadIdx.x;
    const int tr   = tid & 15;      // row group
    const int tc   = tid >> 4;      // col group
    float acc[8][8] = {};

    for (int kc = 0; kc < 8; ++kc) {
        // stage I chunk: 128 rows x 16 k  (512 float4, 2/thread)
        #pragma unroll
        for (int j = 0; j < 2; ++j) {
            int id  = j * 256 + tid;
            int row = id >> 2, kq = id & 3;
            float4 g = ((const float4*)I)[(size_t)(row0 + row) * 32 + kc * 4 + kq];
            sI[kq*4+0][row] = g.x; sI[kq*4+1][row] = g.y;
            sI[kq*4+2][row] = g.z; sI[kq*4+3][row] = g.w;
        }
        // stage W chunk: w1[o][3 + kc*16 + kk]  (scalar, unaligned row of 131)
        {
            int o = tid >> 1, kk0 = (tid & 1) * 8;
            #pragma unroll
            for (int kk = 0; kk < 8; ++kk)
                sW[kk0+kk][o] = w1[(size_t)o * IN_ + 3 + kc*16 + kk0 + kk];
        }
        __syncthreads();
        #pragma unroll
        for (int kk = 0; kk < 16; ++kk) {
            float4 a0 = *(const float4*)&sI[kk][tr*8];
            float4 a1 = *(const float4*)&sI[kk][tr*8+4];
            float4 c0 = *(const float4*)&sW[kk][tc*8];
            float4 c1 = *(const float4*)&sW[kk][tc*8+4];
            float av[8] = {a0.x,a0.y,a0.z,a0.w,a1.x,a1.y,a1.z,a1.w};
            float bv[8] = {c0.x,c0.y,c0.z,c0.w,c1.x,c1.y,c1.z,c1.w};
            #pragma unroll
            for (int i = 0; i < 8; ++i)
                #pragma unroll
                for (int j = 0; j < 8; ++j)
                    acc[i][j] = fmaf(av[i], bv[j], acc[i][j]);
        }
        __syncthreads();
    }

    // epilogue: xyz part + bias + relu, store A
    float wx0[8], wx1[8], wx2[8], bb[8];
    #pragma unroll
    for (int j = 0; j < 8; ++j) {
        int o = tc*8 + j;
        wx0[j] = w1[(size_t)o*IN_+0];
        wx1[j] = w1[(size_t)o*IN_+1];
        wx2[j] = w1[(size_t)o*IN_+2];
        bb[j]  = b1[o];
    }
    #pragma unroll
    for (int i = 0; i < 8; ++i) {
        int r = row0 + tr*8 + i;
        float x0 = x[(size_t)r*3+0], x1 = x[(size_t)r*3+1], x2 = x[(size_t)r*3+2];
        #pragma unroll
        for (int j = 0; j < 8; ++j) {
            float v = acc[i][j] + wx0[j]*x0 + wx1[j]*x1 + wx2[j]*x2 + bb[j];
            acc[i][j] = v > 0.0f ? v : 0.0f;
        }
        float4 o0 = make_float4(acc[i][0], acc[i][1], acc[i][2], acc[i][3]);
        float4 o1 = make_float4(acc[i][4], acc[i][5], acc[i][6], acc[i][7]);
        ((float4*)A)[(size_t)r * 32 + tc*2 + 0] = o0;
        ((float4*)A)[(size_t)r * 32 + tc*2 + 1] = o1;
    }
}

// ---------------------------------------------------------------------------
// K4: Out[b][o][n] = A @ W2^T + b2, stored transposed. Row-blocked micro-tile
// makes each (o, 8 consecutive n) store a pair of float4s.
// ---------------------------------------------------------------------------
__global__ __launch_bounds__(256) void gemm2_kernel(const float* __restrict__ A,
                                                    const float* __restrict__ w2,
                                                    const float* __restrict__ b2,
                                                    float* __restrict__ out) {
    __shared__ float sA[16][132];
    __shared__ float sW[16][132];
    const int row0 = blockIdx.x * 128;
    const int tid  = threadIdx.x;
    const int tr   = tid & 15;
    const int tc   = tid >> 4;
    float acc[8][8] = {};

    for (int kc = 0; kc < 8; ++kc) {
        #pragma unroll
        for (int j = 0; j < 2; ++j) {
            int id  = j * 256 + tid;
            int row = id >> 2, kq = id & 3;
            float4 g = ((const float4*)A)[(size_t)(row0 + row) * 32 + kc * 4 + kq];
            sA[kq*4+0][row] = g.x; sA[kq*4+1][row] = g.y;
            sA[kq*4+2][row] = g.z; sA[kq*4+3][row] = g.w;
            float4 h = ((const float4*)w2)[(size_t)row * 32 + kc * 4 + kq];
            sW[kq*4+0][row] = h.x; sW[kq*4+1][row] = h.y;
            sW[kq*4+2][row] = h.z; sW[kq*4+3][row] = h.w;
        }
        __syncthreads();
        #pragma unroll
        for (int kk = 0; kk < 16; ++kk) {
            float4 a0 = *(const float4*)&sA[kk][tr*8];
            float4 a1 = *(const float4*)&sA[kk][tr*8+4];
            float4 c0 = *(const float4*)&sW[kk][tc*8];
            float4 c1 = *(const float4*)&sW[kk][tc*8+4];
            float av[8] = {a0.x,a0.y,a0.z,a0.w,a1.x,a1.y,a1.z,a1.w};
            float bv[8] = {c0.x,c0.y,c0.z,c0.w,c1.x,c1.y,c1.z,c1.w};
            #pragma unroll
            for (int i = 0; i < 8; ++i)
                #pragma unroll
                for (int j = 0; j < 8; ++j)
                    acc[i][j] = fmaf(av[i], bv[j], acc[i][j]);
        }
        __syncthreads();
    }

    const int b  = row0 >> 15;
    const int n0 = (row0 & (N_-1)) + tr*8;
    #pragma unroll
    for (int j = 0; j < 8; ++j) {
        int o = tc*8 + j;
        float bias = b2[o];
        float4 o0 = make_float4(acc[0][j]+bias, acc[1][j]+bias,
                                acc[2][j]+bias, acc[3][j]+bias);
        float4 o1 = make_float4(acc[4][j]+bias, acc[5][j]+bias,
                                acc[6][j]+bias, acc[7][j]+bias);
        float* dst = out + (((size_t)(b*OUT_ + o)) << 15) + n0;
        *(float4*)dst       = o0;
        *(float4*)(dst + 4) = o1;
    }
}

extern "C" void kernel_launch(void* const* d_in, const int* in_sizes, int n_in,
                              void* d_out, int out_size, void* d_ws, size_t ws_size,
                              hipStream_t stream) {
    const float* x        = (const float*)d_in[0];   // [B,N,3]
    const float* sx       = (const float*)d_in[1];   // [B,M,3]
    const float* features = (const float*)d_in[2];   // [B,M,C]
    const float* w1       = (const float*)d_in[3];   // [128,131]
    const float* b1       = (const float*)d_in[4];   // [128]
    const float* w2       = (const float*)d_in[5];   // [128,128]
    const float* b2       = (const float*)d_in[6];   // [128]
    float* out = (float*)d_out;                      // [B,128,N]

    char* ws = (char*)d_ws;
    int4*  idxb = (int4*)ws;                                   // 1 MB
    float* I    = (float*)(ws + (1u << 20));                   // 32 MB
    float* A    = (float*)(ws + (1u << 20) + ((size_t)B_*N_*C_*4)); // 32 MB

    nn_kernel    <<<dim3(B_*N_/256), dim3(256), 0, stream>>>(x, sx, idxb);
    interp_kernel<<<dim3(B_*N_*32/256), dim3(256), 0, stream>>>(features, idxb, (float4*)I);
    gemm1_kernel <<<dim3(B_*N_/128), dim3(256), 0, stream>>>(I, x, w1, b1, A);
    gemm2_kernel <<<dim3(B_*N_/128), dim3(256), 0, stream>>>(A, w2, b2, out);
}